// Round 1
// baseline (180.194 us; speedup 1.0000x reference)
//
#include <hip/hip_runtime.h>
#include <hip/hip_bf16.h>

typedef __attribute__((ext_vector_type(8))) short short8;
typedef __attribute__((ext_vector_type(4))) float f32x4;
typedef unsigned long long u64;
typedef unsigned short u16;

#define NODES 512
#define HIDDEN 512
#define NEDGES 16384

// ---- helpers ----
static __device__ __forceinline__ u16 f2bf(float f) {
  unsigned u = __float_as_uint(f);
  u += 0x7FFFu + ((u >> 16) & 1u);
  return (u16)(u >> 16);
}

static __device__ __forceinline__ void gld_lds16(const void* g, void* l) {
  __builtin_amdgcn_global_load_lds(
      (const __attribute__((address_space(1))) unsigned int*)g,
      (__attribute__((address_space(3))) unsigned int*)l, 16, 0, 0);
}

// ---- kernel 1: fp32 -> bf16 cast (vectorized) ----
__global__ void cast_f32_bf16(const float* __restrict__ in, u16* __restrict__ out, int n4) {
  int stride = gridDim.x * blockDim.x;
  for (int i = blockIdx.x * blockDim.x + threadIdx.x; i < n4; i += stride) {
    float4 v = reinterpret_cast<const float4*>(in)[i];
    ushort4 o;
    o.x = f2bf(v.x); o.y = f2bf(v.y); o.z = f2bf(v.z); o.w = f2bf(v.w);
    reinterpret_cast<ushort4*>(out)[i] = o;
  }
}

// ---- kernel 2: adjacency bitmask scatter ----
__global__ void mask_scatter(const int* __restrict__ e, u64* __restrict__ bits) {
  int i = blockIdx.x * blockDim.x + threadIdx.x;
  if (i < NEDGES) {
    int src = e[i];            // query node
    int dst = e[NEDGES + i];   // key node
    atomicOr(&bits[src * 8 + (dst >> 6)], 1ull << (dst & 63));
  }
}

// ---- kernel 3: fused QKV GEMM: C[m, j] = sum_k xb[m,k] * W[j,k] + bias[j] ----
// M = 24576, N = 512, K = 512.  z in {0,1,2} selects Q/K/V.
// Output scattered to qkv[z][bs*8+h][node][d] bf16.
__global__ __launch_bounds__(256, 2)
void qkv_gemm(const u16* __restrict__ xb, const u16* __restrict__ wb,
              const float* __restrict__ bq, const float* __restrict__ bk,
              const float* __restrict__ bv, u16* __restrict__ qkv) {
  __shared__ u16 As[128 * 64];
  __shared__ u16 Bs[128 * 64];

  const int m0 = blockIdx.x * 128;
  const int n0 = blockIdx.y * 128;
  const int z  = blockIdx.z;
  const u16* Wz = wb + (size_t)z * (512 * 512);
  const float* bias = (z == 0) ? bq : (z == 1) ? bk : bv;

  const int tid = threadIdx.x;
  const int lane = tid & 63;
  const int w = tid >> 6;
  const int wr = w >> 1, wc = w & 1;

  f32x4 acc[4][4] = {};

  for (int kt = 0; kt < 8; ++kt) {
    const int k0 = kt * 64;
    // stage A and B tiles: 16 chunks of 1KB each (4 per wave)
#pragma unroll
    for (int t = 0; t < 4; ++t) {
      int c = w * 4 + t;
      int row = c * 8 + (lane >> 3);
      int kb = (lane & 7) * 16;  // byte offset within row chunk
      gld_lds16((const char*)xb + ((size_t)(m0 + row) * 512 + k0) * 2 + kb,
                (char*)As + c * 1024);
      gld_lds16((const char*)Wz + ((size_t)(n0 + row) * 512 + k0) * 2 + kb,
                (char*)Bs + c * 1024);
    }
    __syncthreads();
#pragma unroll
    for (int kk = 0; kk < 2; ++kk) {
      short8 a[4], b[4];
      const int kf = kk * 32 + (lane >> 4) * 8;
#pragma unroll
      for (int mi = 0; mi < 4; ++mi) {
        int row = wr * 64 + mi * 16 + (lane & 15);
        a[mi] = *(const short8*)(As + row * 64 + kf);
      }
#pragma unroll
      for (int ni = 0; ni < 4; ++ni) {
        int row = wc * 64 + ni * 16 + (lane & 15);
        b[ni] = *(const short8*)(Bs + row * 64 + kf);
      }
#pragma unroll
      for (int mi = 0; mi < 4; ++mi)
#pragma unroll
        for (int ni = 0; ni < 4; ++ni)
          acc[mi][ni] = __builtin_amdgcn_mfma_f32_16x16x32_bf16(a[mi], b[ni], acc[mi][ni], 0, 0, 0);
    }
    __syncthreads();
  }

  // epilogue: add bias, cast bf16, scatter to head-major layout
#pragma unroll
  for (int ni = 0; ni < 4; ++ni) {
    int j = n0 + wc * 64 + ni * 16 + (lane & 15);
    float bv_ = bias[j];
    int h = j >> 6, d = j & 63;
#pragma unroll
    for (int mi = 0; mi < 4; ++mi) {
#pragma unroll
      for (int r = 0; r < 4; ++r) {
        int m = m0 + wr * 64 + mi * 16 + (lane >> 4) * 4 + r;
        int bs = m >> 9, node = m & 511;
        float v = acc[mi][ni][r] + bv_;
        qkv[(size_t)(z * 384 + bs * 8 + h) * 32768 + node * 64 + d] = f2bf(v);
      }
    }
  }
}

// ---- kernel 4: masked attention, one block per (bh, q-tile of 64) ----
// No-max softmax: p = exp(score/8) on edges, 0 elsewhere; normalize at end.
__global__ __launch_bounds__(256, 2)
void attn_kernel(const u16* __restrict__ qkv, const u64* __restrict__ maskbits,
                 float* __restrict__ out) {
  __shared__ u16 Ks[64 * 64];
  __shared__ u16 Vt[64 * 72];       // transposed V, padded rows (72)
  __shared__ u16 Pl[4][16 * 72];    // per-wave P strip, padded rows (72)

  const int blk = blockIdx.x;
  const int bh = blk >> 3, qt = blk & 7;
  const int bs = bh >> 3, h = bh & 7;
  const int tid = threadIdx.x;
  const int lane = tid & 63;
  const int w = tid >> 6;
  const int q0 = qt * 64;

  const u16* Qg = qkv + (size_t)bh * 32768;
  const u16* Kg = qkv + (size_t)(384 + bh) * 32768;
  const u16* Vg = qkv + (size_t)(768 + bh) * 32768;

  // Q fragments (held in registers for the whole kernel)
  short8 qf[2];
  {
    int row = q0 + w * 16 + (lane & 15);
#pragma unroll
    for (int kk = 0; kk < 2; ++kk)
      qf[kk] = *(const short8*)(Qg + row * 64 + kk * 32 + (lane >> 4) * 8);
  }

  f32x4 o[4] = {};
  float sum4[4] = {0.f, 0.f, 0.f, 0.f};
  const int qrow_base = q0 + w * 16 + (lane >> 4) * 4;

  for (int kt = 0; kt < 8; ++kt) {
    // stage K tile (contiguous 8KB) via global_load_lds
#pragma unroll
    for (int t = 0; t < 2; ++t) {
      int c = w * 2 + t;
      gld_lds16((const char*)(Kg + kt * 4096) + c * 1024 + lane * 16,
                (char*)Ks + c * 1024);
    }
    // stage V transposed (reg-staged)
    {
      int key = tid >> 2, d0 = (tid & 3) * 16;
      short8 v0 = *(const short8*)(Vg + kt * 4096 + key * 64 + d0);
      short8 v1 = *(const short8*)(Vg + kt * 4096 + key * 64 + d0 + 8);
#pragma unroll
      for (int e2 = 0; e2 < 8; ++e2) {
        Vt[(d0 + e2) * 72 + key] = (u16)v0[e2];
        Vt[(d0 + 8 + e2) * 72 + key] = (u16)v1[e2];
      }
    }
    __syncthreads();

    // mask words: 4 q-rows per lane
    u64 mw[4];
#pragma unroll
    for (int r = 0; r < 4; ++r) mw[r] = maskbits[(qrow_base + r) * 8 + kt];

    // S = Q K^T for this wave's 16 q-rows x 64 keys
    f32x4 s[4];
#pragma unroll
    for (int ni = 0; ni < 4; ++ni) {
      int keyr = ni * 16 + (lane & 15);
      short8 b0 = *(const short8*)(Ks + keyr * 64 + (lane >> 4) * 8);
      short8 b1 = *(const short8*)(Ks + keyr * 64 + 32 + (lane >> 4) * 8);
      f32x4 zacc = {};
      zacc = __builtin_amdgcn_mfma_f32_16x16x32_bf16(qf[0], b0, zacc, 0, 0, 0);
      s[ni] = __builtin_amdgcn_mfma_f32_16x16x32_bf16(qf[1], b1, zacc, 0, 0, 0);
    }

    // p = exp(score/8) where edge exists; write P strip to LDS (bf16)
#pragma unroll
    for (int ni = 0; ni < 4; ++ni) {
      int kl = ni * 16 + (lane & 15);
#pragma unroll
      for (int r = 0; r < 4; ++r) {
        float p = ((mw[r] >> kl) & 1ull) ? __expf(s[ni][r] * 0.125f) : 0.0f;
        sum4[r] += p;
        Pl[w][((lane >> 4) * 4 + r) * 72 + kl] = f2bf(p);
      }
    }
    __syncthreads();

    // O += P V  (A = P[q][key] from LDS, B = V^T[d][key] from LDS)
    short8 pa[2];
#pragma unroll
    for (int kk = 0; kk < 2; ++kk)
      pa[kk] = *(const short8*)(&Pl[w][(lane & 15) * 72 + kk * 32 + (lane >> 4) * 8]);
#pragma unroll
    for (int ni = 0; ni < 4; ++ni) {
#pragma unroll
      for (int kk = 0; kk < 2; ++kk) {
        short8 vb = *(const short8*)(Vt + (ni * 16 + (lane & 15)) * 72 + kk * 32 + (lane >> 4) * 8);
        o[ni] = __builtin_amdgcn_mfma_f32_16x16x32_bf16(pa[kk], vb, o[ni], 0, 0, 0);
      }
    }
    __syncthreads();
  }

  // row-sum reduce across the 16 lanes holding each row, then normalize+store
#pragma unroll
  for (int r = 0; r < 4; ++r) {
    float s_ = sum4[r];
    s_ += __shfl_xor(s_, 1);
    s_ += __shfl_xor(s_, 2);
    s_ += __shfl_xor(s_, 4);
    s_ += __shfl_xor(s_, 8);
    sum4[r] = 1.0f / s_;
  }
#pragma unroll
  for (int ni = 0; ni < 4; ++ni) {
    int d = ni * 16 + (lane & 15);
#pragma unroll
    for (int r = 0; r < 4; ++r) {
      int node = qrow_base + r;
      out[(size_t)bs * 512 * 512 + (size_t)node * 512 + h * 64 + d] = o[ni][r] * sum4[r];
    }
  }
}

// ---- launcher ----
extern "C" void kernel_launch(void* const* d_in, const int* in_sizes, int n_in,
                              void* d_out, int out_size, void* d_ws, size_t ws_size,
                              hipStream_t stream) {
  const float* x  = (const float*)d_in[0];
  const int*   e  = (const int*)d_in[1];
  const float* Wq = (const float*)d_in[2];
  const float* bq = (const float*)d_in[3];
  const float* Wk = (const float*)d_in[4];
  const float* bk = (const float*)d_in[5];
  const float* Wv = (const float*)d_in[6];
  const float* bv = (const float*)d_in[7];
  float* out = (float*)d_out;

  char* ws = (char*)d_ws;
  u16* xb   = (u16*)(ws);                 // 24576*512 bf16 = 25165824 B
  u16* wb   = (u16*)(ws + 25165824);      // 3*512*512 bf16 = 1572864 B
  u16* qkv  = (u16*)(ws + 26738688);      // 3*384*512*64 bf16 = 75497472 B
  u64* mb   = (u64*)(ws + 102236160);     // 512*8 u64 = 32768 B

  hipMemsetAsync(mb, 0, 512 * 8 * sizeof(u64), stream);
  mask_scatter<<<(NEDGES + 255) / 256, 256, 0, stream>>>(e, mb);

  cast_f32_bf16<<<2048, 256, 0, stream>>>(x, xb, (24576 * 512) / 4);
  cast_f32_bf16<<<256, 256, 0, stream>>>(Wq, wb + 0 * 262144, 65536);
  cast_f32_bf16<<<256, 256, 0, stream>>>(Wk, wb + 1 * 262144, 65536);
  cast_f32_bf16<<<256, 256, 0, stream>>>(Wv, wb + 2 * 262144, 65536);

  qkv_gemm<<<dim3(192, 4, 3), 256, 0, stream>>>(xb, wb, bq, bk, bv, qkv);
  attn_kernel<<<48 * 8 * 8, 256, 0, stream>>>(qkv, mb, out);
}

// Round 2
// 166.822 us; speedup vs baseline: 1.0802x; 1.0802x over previous
//
#include <hip/hip_runtime.h>
#include <hip/hip_bf16.h>

typedef __attribute__((ext_vector_type(8))) short short8;
typedef __attribute__((ext_vector_type(4))) float f32x4;
typedef __attribute__((ext_vector_type(4))) unsigned int u32x4;
typedef unsigned long long u64;
typedef unsigned short u16;

#define NODES 512
#define HIDDEN 512
#define NEDGES 16384

// ---- helpers ----
static __device__ __forceinline__ u16 f2bf(float f) {
  unsigned u = __float_as_uint(f);
  u += 0x7FFFu + ((u >> 16) & 1u);
  return (u16)(u >> 16);
}

static __device__ __forceinline__ void gld_lds16(const void* g, void* l) {
  __builtin_amdgcn_global_load_lds(
      (const __attribute__((address_space(1))) unsigned int*)g,
      (__attribute__((address_space(3))) unsigned int*)l, 16, 0, 0);
}

// ---- kernel 1: fp32 -> bf16 cast (vectorized) ----
__global__ void cast_f32_bf16(const float* __restrict__ in, u16* __restrict__ out, int n4) {
  int stride = gridDim.x * blockDim.x;
  for (int i = blockIdx.x * blockDim.x + threadIdx.x; i < n4; i += stride) {
    float4 v = reinterpret_cast<const float4*>(in)[i];
    ushort4 o;
    o.x = f2bf(v.x); o.y = f2bf(v.y); o.z = f2bf(v.z); o.w = f2bf(v.w);
    reinterpret_cast<ushort4*>(out)[i] = o;
  }
}

// ---- kernel 2: adjacency bitmask scatter ----
__global__ void mask_scatter(const int* __restrict__ e, u64* __restrict__ bits) {
  int i = blockIdx.x * blockDim.x + threadIdx.x;
  if (i < NEDGES) {
    int src = e[i];            // query node
    int dst = e[NEDGES + i];   // key node
    atomicOr(&bits[src * 8 + (dst >> 6)], 1ull << (dst & 63));
  }
}

// ---- kernel 3: fused QKV GEMM: C[m, j] = sum_k xb[m,k] * W[j,k] + bias[j] ----
// M = 24576, N = 512, K = 512.  z in {0,1,2} selects Q/K/V.
// z=0,1: head-major qkv[z][bh][node][d].  z=2: TRANSPOSED vt[bh][d][node].
__global__ __launch_bounds__(256, 2)
void qkv_gemm(const u16* __restrict__ xb, const u16* __restrict__ wb,
              const float* __restrict__ bq, const float* __restrict__ bk,
              const float* __restrict__ bv, u16* __restrict__ qkv) {
  __shared__ u16 As[128 * 64];
  __shared__ u16 Bs[128 * 64];

  const int m0 = blockIdx.x * 128;
  const int n0 = blockIdx.y * 128;
  const int z  = blockIdx.z;
  const u16* Wz = wb + (size_t)z * (512 * 512);
  const float* bias = (z == 0) ? bq : (z == 1) ? bk : bv;

  const int tid = threadIdx.x;
  const int lane = tid & 63;
  const int w = tid >> 6;
  const int wr = w >> 1, wc = w & 1;

  f32x4 acc[4][4] = {};

  for (int kt = 0; kt < 8; ++kt) {
    const int k0 = kt * 64;
#pragma unroll
    for (int t = 0; t < 4; ++t) {
      int c = w * 4 + t;
      int row = c * 8 + (lane >> 3);
      int kb = (lane & 7) * 16;
      gld_lds16((const char*)xb + ((size_t)(m0 + row) * 512 + k0) * 2 + kb,
                (char*)As + c * 1024);
      gld_lds16((const char*)Wz + ((size_t)(n0 + row) * 512 + k0) * 2 + kb,
                (char*)Bs + c * 1024);
    }
    __syncthreads();
#pragma unroll
    for (int kk = 0; kk < 2; ++kk) {
      short8 a[4], b[4];
      const int kf = kk * 32 + (lane >> 4) * 8;
#pragma unroll
      for (int mi = 0; mi < 4; ++mi) {
        int row = wr * 64 + mi * 16 + (lane & 15);
        a[mi] = *(const short8*)(As + row * 64 + kf);
      }
#pragma unroll
      for (int ni = 0; ni < 4; ++ni) {
        int row = wc * 64 + ni * 16 + (lane & 15);
        b[ni] = *(const short8*)(Bs + row * 64 + kf);
      }
#pragma unroll
      for (int mi = 0; mi < 4; ++mi)
#pragma unroll
        for (int ni = 0; ni < 4; ++ni)
          acc[mi][ni] = __builtin_amdgcn_mfma_f32_16x16x32_bf16(a[mi], b[ni], acc[mi][ni], 0, 0, 0);
    }
    __syncthreads();
  }

  // epilogue
#pragma unroll
  for (int ni = 0; ni < 4; ++ni) {
    int jcol = n0 + wc * 64 + ni * 16 + (lane & 15);
    float bv_ = bias[jcol];
    int h = jcol >> 6, d = jcol & 63;
#pragma unroll
    for (int mi = 0; mi < 4; ++mi) {
      int m = m0 + wr * 64 + mi * 16 + (lane >> 4) * 4;
      int bs = m >> 9, node = m & 511;  // node multiple of 4
      if (z == 2) {
        ushort4 pk;
#pragma unroll
        for (int r = 0; r < 4; ++r) pk[r] = f2bf(acc[mi][ni][r] + bv_);
        *reinterpret_cast<ushort4*>(qkv + (size_t)768 * 32768 +
            ((size_t)(bs * 8 + h) * 64 + d) * 512 + node) = pk;
      } else {
#pragma unroll
        for (int r = 0; r < 4; ++r) {
          float v = acc[mi][ni][r] + bv_;
          qkv[(size_t)(z * 384 + bs * 8 + h) * 32768 + (node + r) * 64 + d] = f2bf(v);
        }
      }
    }
  }
}

// ---- kernel 4: masked attention ----
// Swapped QK^T (A=K, B=Q): lane holds P row-slice (q = lane&15, 16 keys).
// In-register P->bf16 via v_cvt_pk_bf16_f32 + ds_bpermute to PV A-frag.
// K and V^T staged via global_load_lds with XOR-swizzle (pre-swizzled source).
__global__ __launch_bounds__(256, 2)
void attn_kernel(const u16* __restrict__ qkv, const u64* __restrict__ maskbits,
                 float* __restrict__ out) {
  __shared__ u16 KS[2][64 * 64];
  __shared__ u16 VS[2][64 * 64];

  // XCD grouping: the 8 q-tiles of one bh land on one XCD, qt-consecutive.
  const int blk = blockIdx.x;
  const int bh = (blk & 7) * 48 + (blk >> 6);
  const int qt = (blk >> 3) & 7;
  const int bs = bh >> 3, h = bh & 7;
  const int tid = threadIdx.x;
  const int lane = tid & 63;
  const int w = tid >> 6;
  const int j = lane >> 4;
  const int q0 = qt * 64;

  const u16* Qg  = qkv + (size_t)bh * 32768;
  const u16* Kg  = qkv + (size_t)(384 + bh) * 32768;
  const u16* VTg = qkv + (size_t)(768 + bh) * 32768;  // [d=64][node=512]

  // Q fragments (B operand): row = q = lane&15
  short8 qf[2];
  {
    int row = q0 + w * 16 + (lane & 15);
#pragma unroll
    for (int kk = 0; kk < 2; ++kk)
      qf[kk] = *(const short8*)(Qg + row * 64 + kk * 32 + j * 8);
  }

#define STAGE(ktile, bb) do {                                                   \
    const char* kg_ = (const char*)Kg + (ktile) * 8192;                         \
    const char* vg_ = (const char*)VTg + (ktile) * 128;                         \
    int ro_ = (lane >> 3);                                                      \
    int so_ = ((lane & 7) ^ ro_) << 4;                                          \
    _Pragma("unroll")                                                           \
    for (int t_ = 0; t_ < 2; ++t_) {                                            \
      int c_ = w * 2 + t_;                                                      \
      gld_lds16(kg_ + c_ * 1024 + ro_ * 128 + so_, (char*)&KS[bb][0] + c_ * 1024); \
      gld_lds16(vg_ + (c_ * 8 + ro_) * 1024 + so_, (char*)&VS[bb][0] + c_ * 1024); \
    }                                                                           \
  } while (0)

  f32x4 o[4] = {};
  float lsum = 0.0f;

  STAGE(0, 0);
  __syncthreads();
  int cur = 0;

  for (int kt = 0; kt < 8; ++kt) {
    // mask word: one u64 per lane (row = this lane's q)
    u64 mw = maskbits[(q0 + w * 16 + (lane & 15)) * 8 + kt];

    if (kt < 7) STAGE(kt + 1, cur ^ 1);

    // QK^T: A = K rows (keys), B = Q rows (q). C: col=lane&15=q, row=key.
    const u16* Kb = KS[cur];
    f32x4 st[4];
#pragma unroll
    for (int ni = 0; ni < 4; ++ni) {
      int key = ni * 16 + (lane & 15);
      short8 ka0 = *(const short8*)((const char*)Kb + key * 128 + (((0 + j) ^ (lane & 7)) << 4));
      short8 ka1 = *(const short8*)((const char*)Kb + key * 128 + (((4 + j) ^ (lane & 7)) << 4));
      f32x4 z = {};
      z = __builtin_amdgcn_mfma_f32_16x16x32_bf16(ka0, qf[0], z, 0, 0, 0);
      st[ni] = __builtin_amdgcn_mfma_f32_16x16x32_bf16(ka1, qf[1], st[ni] = z, 0, 0, 0);
    }

    // P = mask ? exp(s/8) : 0; pack to bf16 pairs in-register
    unsigned p2[4][2];
#pragma unroll
    for (int ni = 0; ni < 4; ++ni) {
      unsigned m4 = (unsigned)(mw >> (ni * 16 + j * 4)) & 0xFu;
      float pr[4];
#pragma unroll
      for (int r = 0; r < 4; ++r) {
        float e = __expf(st[ni][r] * 0.125f);
        pr[r] = ((m4 >> r) & 1u) ? e : 0.0f;
        lsum += pr[r];
      }
      asm("v_cvt_pk_bf16_f32 %0, %1, %2" : "=v"(p2[ni][0]) : "v"(pr[0]), "v"(pr[1]));
      asm("v_cvt_pk_bf16_f32 %0, %1, %2" : "=v"(p2[ni][1]) : "v"(pr[2]), "v"(pr[3]));
    }

    // redistribute P to PV A-frag layout: lane needs keys kk*32 + j*8 + {0..7}
    u32x4 paw[2];
#pragma unroll
    for (int kk = 0; kk < 2; ++kk) {
#pragma unroll
      for (int w2 = 0; w2 < 4; ++w2) {
        int src = (lane & 15) + ((lane & 16) << 1) + ((w2 >> 1) << 4);
        unsigned lo = __shfl(p2[kk * 2][w2 & 1], src);
        unsigned hi = __shfl(p2[kk * 2 + 1][w2 & 1], src);
        paw[kk][w2] = (j & 2) ? hi : lo;
      }
    }

    // O += P V : A = P (q rows), B = V^T rows (d), contraction over keys
    const u16* Vb = VS[cur];
#pragma unroll
    for (int ni = 0; ni < 4; ++ni) {
      int d = ni * 16 + (lane & 15);
      short8 vb0 = *(const short8*)((const char*)Vb + d * 128 + (((0 + j) ^ (lane & 7)) << 4));
      short8 vb1 = *(const short8*)((const char*)Vb + d * 128 + (((4 + j) ^ (lane & 7)) << 4));
      o[ni] = __builtin_amdgcn_mfma_f32_16x16x32_bf16(__builtin_bit_cast(short8, paw[0]), vb0, o[ni], 0, 0, 0);
      o[ni] = __builtin_amdgcn_mfma_f32_16x16x32_bf16(__builtin_bit_cast(short8, paw[1]), vb1, o[ni], 0, 0, 0);
    }

    __syncthreads();
    cur ^= 1;
  }
#undef STAGE

  // row sums: reduce across j-groups (same q = lane&15)
  float tsum = lsum + __shfl_xor(lsum, 16);
  tsum += __shfl_xor(tsum, 32);
  float inv = 1.0f / tsum;
  float invr[4];
#pragma unroll
  for (int r = 0; r < 4; ++r) invr[r] = __shfl(inv, j * 4 + r);

  // store: lane holds q rows j*4+r, cols d = ni*16 + (lane&15)
#pragma unroll
  for (int ni = 0; ni < 4; ++ni) {
    int d = ni * 16 + (lane & 15);
#pragma unroll
    for (int r = 0; r < 4; ++r) {
      int node = q0 + w * 16 + j * 4 + r;
      out[(size_t)bs * 262144 + (size_t)node * 512 + h * 64 + d] = o[ni][r] * invr[r];
    }
  }
}

// ---- launcher ----
extern "C" void kernel_launch(void* const* d_in, const int* in_sizes, int n_in,
                              void* d_out, int out_size, void* d_ws, size_t ws_size,
                              hipStream_t stream) {
  const float* x  = (const float*)d_in[0];
  const int*   e  = (const int*)d_in[1];
  const float* Wq = (const float*)d_in[2];
  const float* bq = (const float*)d_in[3];
  const float* Wk = (const float*)d_in[4];
  const float* bk = (const float*)d_in[5];
  const float* Wv = (const float*)d_in[6];
  const float* bv = (const float*)d_in[7];
  float* out = (float*)d_out;

  char* ws = (char*)d_ws;
  u16* xb   = (u16*)(ws);                 // 24576*512 bf16 = 25165824 B
  u16* wb   = (u16*)(ws + 25165824);      // 3*512*512 bf16 = 1572864 B
  u16* qkv  = (u16*)(ws + 26738688);      // 3*384*512*64 bf16 = 75497472 B
  u64* mb   = (u64*)(ws + 102236160);     // 512*8 u64 = 32768 B

  hipMemsetAsync(mb, 0, 512 * 8 * sizeof(u64), stream);
  mask_scatter<<<(NEDGES + 255) / 256, 256, 0, stream>>>(e, mb);

  cast_f32_bf16<<<2048, 256, 0, stream>>>(x, xb, (24576 * 512) / 4);
  cast_f32_bf16<<<256, 256, 0, stream>>>(Wq, wb + 0 * 262144, 65536);
  cast_f32_bf16<<<256, 256, 0, stream>>>(Wk, wb + 1 * 262144, 65536);
  cast_f32_bf16<<<256, 256, 0, stream>>>(Wv, wb + 2 * 262144, 65536);

  qkv_gemm<<<dim3(192, 4, 3), 256, 0, stream>>>(xb, wb, bq, bk, bv, qkv);
  attn_kernel<<<48 * 8 * 8, 256, 0, stream>>>(qkv, mb, out);
}